// Round 1
// baseline (166.528 us; speedup 1.0000x reference)
//
#include <hip/hip_runtime.h>
#include <stdint.h>

#define IN_F 512
#define OUT_F 512
#define NROWS 8192
#define NSLOT 12                 // 11 spline slots + 1 base(x) slot per in-feature
#define KTOT (IN_F * NSLOT)      // 6144
#define K16S (KTOT / 16)         // 384 k16-steps
#define SW_ROW (IN_F * 11)       // 5632 floats per output row of spline_weight
#define KC_PAD 776               // prep kcol row stride (ushorts)
#define AROW 120                 // A-tile row stride (ushorts): 96 slots + pad

typedef __bf16 bf16x8 __attribute__((ext_vector_type(8)));
typedef __bf16 bf16x2 __attribute__((ext_vector_type(2)));
typedef float f32x16 __attribute__((ext_vector_type(16)));

// frag-linear B: uint4 index (ntg*384 + k16)*64 + lane -> 8 bf16 =
//   B[k16*16+(lane>>5)*8+j][ntg*32 + (lane&31)],  k = f*12 + j_slot
__device__ ushort g_Wb[(K16S * 16 + 1) * 512];   // 6.3 MB

__device__ __forceinline__ ushort f2bf(float f) {
    uint32_t u = __builtin_bit_cast(uint32_t, f);
    u += 0x7FFFu + ((u >> 16) & 1u);          // RNE
    return (ushort)(u >> 16);
}

// ---- prep: weights -> frag-linear g_Wb, AND zero d_out (one dispatch) ------
__global__ __launch_bounds__(256) void prep_weights(const float* __restrict__ bw,
                                                    const float* __restrict__ sw,
                                                    float* __restrict__ out) {
    __shared__ __align__(16) ushort kcol[16 * KC_PAD];    // 24.8 KB
    const int t  = threadIdx.x;
    const int b  = blockIdx.x;
    const int nt = b & 15;                    // 32-out tile
    const int kg = (b >> 4) & 7;              // 64-feat group -> k16 [kg*48,+48)
    const int hv = b >> 7;                    // out half (16 outs)
    const int o0 = nt * 32 + hv * 16;
    const int f0 = kg * 64;

    // zero this block's slice of d_out (4096 float4 per block, coalesced)
    {
        float4* o4 = (float4*)out;
        const float4 z = make_float4(0.f, 0.f, 0.f, 0.f);
        #pragma unroll
        for (int i = 0; i < 16; ++i) o4[(size_t)b * 4096 + i * 256 + t] = z;
    }

    // phase 1: sw slices -> bf16 k-columns in LDS (16 rows x 704 floats)
    {
        const int o_l = t >> 4;               // 0..15
        const int tr  = t & 15;               // 16 threads per row
        const float* swr = sw + (size_t)(o0 + o_l) * SW_ROW + (size_t)f0 * 11;
        #pragma unroll
        for (int i = 0; i < 11; ++i) {
            int p4 = tr + i * 16;             // float4 idx 0..175
            float4 v = ((const float4*)swr)[p4];
            uint pos = (uint)p4 * 4;
            #pragma unroll
            for (int c = 0; c < 4; ++c) {
                uint pc = pos + c;            // 0..703
                uint fl = pc / 11u;
                uint j  = pc - fl * 11u;
                float val = (c == 0) ? v.x : (c == 1) ? v.y : (c == 2) ? v.z : v.w;
                kcol[o_l * KC_PAD + fl * NSLOT + j] = f2bf(val);
            }
        }
        #pragma unroll
        for (int i = 0; i < 4; ++i) {
            int fl = tr * 4 + i;              // 0..63
            kcol[o_l * KC_PAD + fl * NSLOT + 11] =
                f2bf(bw[(size_t)(o0 + o_l) * IN_F + f0 + fl]);
        }
    }
    __syncthreads();

    // phase 2: frag-linear 16B stores (16-lane, 256B bursts)
    {
        const int ol16 = t & 15;
        const int ch   = t >> 4;              // 0..15
        #pragma unroll
        for (int i = 0; i < 6; ++i) {
            int idx  = ch + i * 16;           // 0..95
            int k16l = idx >> 1;
            int hf   = idx & 1;
            uint4 val = *(const uint4*)&kcol[ol16 * KC_PAD + k16l * 16 + hf * 8];
            ((uint4*)g_Wb)[((size_t)nt * K16S + kg * 48 + k16l) * 64 + hf * 32 + hv * 16 + ol16] = val;
        }
    }
}

// ---- basis eval: 12 bf16 slots packed into p[0..5] -------------------------
__device__ __forceinline__ void eval12(float xx, uint p[6]) {
    float wpos = (xx + 1.0f) * 7.0f;
    float fi = floorf(wpos);
    int   i  = (int)fi;
    float u  = wpos - fi;
    bool inr = (xx >= -1.0f) && (xx < 1.0f);
    int   q  = i - 3;
    float um = 1.0f - u;
    float uu = u * u, u3 = uu * u;
    const float C6 = 1.0f / 6.0f;
    float s0 = (inr && q >= 0) ? C6 : 0.0f;
    float s1 = (inr && q >= -1 && q <= 9) ? C6 : 0.0f;
    float s2 = (inr && q >= -2 && q <= 8) ? C6 : 0.0f;
    float s3 = (inr && q <= 7) ? C6 : 0.0f;
    float b0 = um * um * um * s0;
    float b1 = fmaf(3.0f, u3, fmaf(-6.0f, uu, 4.0f)) * s1;
    float b2 = fmaf(-3.0f, u3, fmaf(3.0f, uu, fmaf(3.0f, u, 1.0f))) * s2;
    float b3 = u3 * s3;
    bf16x2 k01; k01[0] = (__bf16)b0; k01[1] = (__bf16)b1;
    bf16x2 k23; k23[0] = (__bf16)b2; k23[1] = (__bf16)b3;
    uint K01 = __builtin_bit_cast(uint, k01);
    uint K23 = __builtin_bit_cast(uint, k23);
    int r  = q & 1;
    int e0 = q & ~1;
    uint P0 = r ? (K01 << 16) : K01;
    uint P1 = r ? ((K01 >> 16) | (K23 << 16)) : K23;
    uint P2 = r ? (K23 >> 16) : 0u;
    #pragma unroll
    for (int pi = 0; pi < 6; ++pi) {
        int d = 2 * pi - e0;
        p[pi] = (d == 0) ? P0 : (d == 2) ? P1 : (d == 4) ? P2 : 0u;
    }
    p[5] = (p[5] & 0xFFFFu) | ((uint)f2bf(xx) << 16);   // slot 11 = raw x
}

// stage 4 features -> 96 B via 12x ds_write_b64 (low-conflict pattern)
__device__ __forceinline__ void stage4(float4 xv, ushort* dst) {
    uint p[4][6];
    eval12(xv.x, p[0]);
    eval12(xv.y, p[1]);
    eval12(xv.z, p[2]);
    eval12(xv.w, p[3]);
    #pragma unroll
    for (int c = 0; c < 4; ++c) {
        uint2 w0; w0.x = p[c][0]; w0.y = p[c][1];
        uint2 w1; w1.x = p[c][2]; w1.y = p[c][3];
        uint2 w2; w2.x = p[c][4]; w2.y = p[c][5];
        *(uint2*)&dst[c * 12 + 0] = w0;
        *(uint2*)&dst[c * 12 + 4] = w1;
        *(uint2*)&dst[c * 12 + 8] = w2;
    }
}

// ---- fused GEMM: block 128x128, single-buffer A, 3 blocks/CU ---------------
// grid 1024: bx = mb*16 + cg*4 + kp  ->  XCD = (cg*4+kp)%8: 2 cg/XCD (B 3.1MB, L2-fit)
__global__ __launch_bounds__(256, 3) void kan_gemm(const float* __restrict__ x,
                                                   float* __restrict__ out) {
    __shared__ __align__(16) ushort As[128 * AROW];   // 30720 B

    const int t    = threadIdx.x;
    const int lane = t & 63;
    const int wv   = t >> 6;          // 0..3
    const int wr   = wv >> 1;         // wave M half
    const int wc   = wv & 1;          // wave N half
    const int ln31 = lane & 31;
    const int half = lane >> 5;

    const int bx = blockIdx.x;
    const int mb = bx >> 4;           // 0..63
    const int cg = (bx >> 2) & 3;     // 128-col group
    const int kp = bx & 3;            // K quarter (128 feats, 16 groups)
    const int row_base = mb * 128;

    // staging: thread -> (row, 4 feats)
    const int srow = t >> 1;
    const int fq   = t & 1;
    const float* xp = x + (size_t)(row_base + srow) * IN_F + kp * 128 + fq * 4;
    ushort* const sb = &As[srow * AROW + fq * 48];

    const int ntg0 = cg * 4 + wc * 2;
    const uint4* Bp0 = (const uint4*)g_Wb + (size_t)ntg0 * K16S * 64 + lane;
    const uint4* Bp1 = Bp0 + (size_t)K16S * 64;

    f32x16 acc[2][2] = {};

    float4 xv = *(const float4*)xp;   // group 0 of this K-quarter

    #pragma unroll 1
    for (int gi = 0; gi < 16; ++gi) {
        const int g = kp * 16 + gi;   // global 8-feat group 0..63
        // B frags for this group
        uint4 breg[6][2];
        #pragma unroll
        for (int ks = 0; ks < 6; ++ks) {
            breg[ks][0] = Bp0[(size_t)(g * 6 + ks) * 64];
            breg[ks][1] = Bp1[(size_t)(g * 6 + ks) * 64];
        }
        // x prefetch for next group (clamped)
        const int gn = (gi + 1 < 16) ? gi + 1 : gi;
        float4 xn = *(const float4*)(xp + gn * 8);

        __syncthreads();              // prior iteration's A-frag reads done
        stage4(xv, sb);
        __syncthreads();              // publish A-tile

        #pragma unroll
        for (int ks = 0; ks < 6; ++ks) {
            uint4 a0 = *(const uint4*)&As[(wr * 64 + ln31) * AROW + ks * 16 + half * 8];
            uint4 a1 = *(const uint4*)&As[(wr * 64 + 32 + ln31) * AROW + ks * 16 + half * 8];
            bf16x8 af0 = __builtin_bit_cast(bf16x8, a0);
            bf16x8 af1 = __builtin_bit_cast(bf16x8, a1);
            bf16x8 bf0 = __builtin_bit_cast(bf16x8, breg[ks][0]);
            bf16x8 bf1 = __builtin_bit_cast(bf16x8, breg[ks][1]);
            acc[0][0] = __builtin_amdgcn_mfma_f32_32x32x16_bf16(af0, bf0, acc[0][0], 0, 0, 0);
            acc[0][1] = __builtin_amdgcn_mfma_f32_32x32x16_bf16(af0, bf1, acc[0][1], 0, 0, 0);
            acc[1][0] = __builtin_amdgcn_mfma_f32_32x32x16_bf16(af1, bf0, acc[1][0], 0, 0, 0);
            acc[1][1] = __builtin_amdgcn_mfma_f32_32x32x16_bf16(af1, bf1, acc[1][1], 0, 0, 0);
        }
        xv = xn;
    }

    // epilogue: C layout col=lane&31, row=(reg&3)+8*(reg>>2)+4*(lane>>5)
    #pragma unroll
    for (int mt = 0; mt < 2; ++mt) {
        #pragma unroll
        for (int nt2 = 0; nt2 < 2; ++nt2) {
            int rb = row_base + wr * 64 + mt * 32 + 4 * half;
            int cc = cg * 128 + wc * 64 + nt2 * 32 + ln31;
            #pragma unroll
            for (int reg = 0; reg < 16; ++reg) {
                int rr = rb + (reg & 3) + 8 * (reg >> 2);
                unsafeAtomicAdd(&out[(size_t)rr * OUT_F + cc], acc[mt][nt2][reg]);
            }
        }
    }
}

extern "C" void kernel_launch(void* const* d_in, const int* in_sizes, int n_in,
                              void* d_out, int out_size, void* d_ws, size_t ws_size,
                              hipStream_t stream) {
    const float* x  = (const float*)d_in[0];
    const float* bw = (const float*)d_in[1];
    const float* sw = (const float*)d_in[2];
    float* out = (float*)d_out;
    hipLaunchKernelGGL(prep_weights, dim3(256), dim3(256), 0, stream, bw, sw, out);
    hipLaunchKernelGGL(kan_gemm, dim3(1024), dim3(256), 0, stream, x, out);
}

// Round 2
// 165.424 us; speedup vs baseline: 1.0067x; 1.0067x over previous
//
#include <hip/hip_runtime.h>
#include <stdint.h>

#define IN_F 512
#define OUT_F 512
#define NROWS 8192
#define NSLOT 12                 // 11 spline slots + 1 base(x) slot per in-feature
#define KTOT (IN_F * NSLOT)      // 6144
#define K16S (KTOT / 16)         // 384 k16-steps
#define SW_ROW (IN_F * 11)       // 5632 floats per output row of spline_weight
#define KC_PAD 776               // prep kcol row stride (ushorts)
#define AROW 120                 // A-tile row stride (ushorts): 96 slots + pad

typedef __bf16 bf16x8 __attribute__((ext_vector_type(8)));
typedef __bf16 bf16x2 __attribute__((ext_vector_type(2)));
typedef float f32x16 __attribute__((ext_vector_type(16)));

// frag-linear B: uint4 index (ntg*384 + k16)*64 + lane -> 8 bf16 =
//   B[k16*16+(lane>>5)*8+j][ntg*32 + (lane&31)],  k = f*12 + j_slot
__device__ ushort g_Wb[(K16S * 16 + 1) * 512];   // 6.3 MB

__device__ __forceinline__ ushort f2bf(float f) {
    uint32_t u = __builtin_bit_cast(uint32_t, f);
    u += 0x7FFFu + ((u >> 16) & 1u);          // RNE
    return (ushort)(u >> 16);
}

// ---- prep: weights -> frag-linear g_Wb, AND zero d_out (one dispatch) ------
// R1: 4x more blocks (1024), 4 out-rows per block, to fix 1-wave/SIMD latency
// exposure (prep was ~70us of the 166us total at 256 blocks).
__global__ __launch_bounds__(256) void prep_weights(const float* __restrict__ bw,
                                                    const float* __restrict__ sw,
                                                    float* __restrict__ out) {
    __shared__ __align__(16) ushort kcol[4 * KC_PAD];    // 6.2 KB
    const int t  = threadIdx.x;
    const int b  = blockIdx.x;
    const int nt = b & 15;                    // 32-out tile
    const int kg = (b >> 4) & 7;              // 64-feat group -> k16 [kg*48,+48)
    const int hq = b >> 7;                    // 0..7
    const int hv = hq >> 2;                   // out half (16 outs)
    const int qr = hq & 3;                    // quarter of the half (4 outs)
    const int o0 = nt * 32 + hv * 16 + qr * 4;
    const int f0 = kg * 64;

    // zero this block's slice of d_out (1024 float4 per block, coalesced)
    {
        float4* o4 = (float4*)out;
        const float4 z = make_float4(0.f, 0.f, 0.f, 0.f);
        #pragma unroll
        for (int i = 0; i < 4; ++i) o4[(size_t)b * 1024 + i * 256 + t] = z;
    }

    // phase 1: sw slices -> bf16 k-columns in LDS (4 rows x 704 floats)
    {
        const int o_l = t >> 6;               // 0..3
        const int tr  = t & 63;               // 64 threads per row
        const float* swr = sw + (size_t)(o0 + o_l) * SW_ROW + (size_t)f0 * 11;
        #pragma unroll
        for (int i = 0; i < 3; ++i) {
            int p4 = tr + i * 64;             // float4 idx 0..175
            if (p4 < 176) {
                float4 v = ((const float4*)swr)[p4];
                uint pos = (uint)p4 * 4;
                #pragma unroll
                for (int c = 0; c < 4; ++c) {
                    uint pc = pos + c;        // 0..703
                    uint fl = pc / 11u;
                    uint j  = pc - fl * 11u;
                    float val = (c == 0) ? v.x : (c == 1) ? v.y : (c == 2) ? v.z : v.w;
                    kcol[o_l * KC_PAD + fl * NSLOT + j] = f2bf(val);
                }
            }
        }
        // base weight -> slot 11 (64 feats, one per thread-in-row)
        kcol[o_l * KC_PAD + tr * NSLOT + 11] =
            f2bf(bw[(size_t)(o0 + o_l) * IN_F + f0 + tr]);
    }
    __syncthreads();

    // phase 2: frag-linear 16B stores (4 rows x 96 uint4 = 384 per block)
    {
        const int ol4 = t & 3;                // row within block
        const int ch  = t >> 2;               // 0..63
        #pragma unroll
        for (int i = 0; i < 2; ++i) {
            int idx = ch + i * 64;            // 0..127, valid < 96
            if (idx < 96) {
                int k16l = idx >> 1;
                int hf   = idx & 1;
                uint4 val = *(const uint4*)&kcol[ol4 * KC_PAD + k16l * 16 + hf * 8];
                ((uint4*)g_Wb)[((size_t)nt * K16S + kg * 48 + k16l) * 64
                               + hf * 32 + hv * 16 + qr * 4 + ol4] = val;
            }
        }
    }
}

// ---- basis eval: 12 bf16 slots packed into p[0..5] -------------------------
__device__ __forceinline__ void eval12(float xx, uint p[6]) {
    float wpos = (xx + 1.0f) * 7.0f;
    float fi = floorf(wpos);
    int   i  = (int)fi;
    float u  = wpos - fi;
    bool inr = (xx >= -1.0f) && (xx < 1.0f);
    int   q  = i - 3;
    float um = 1.0f - u;
    float uu = u * u, u3 = uu * u;
    const float C6 = 1.0f / 6.0f;
    float s0 = (inr && q >= 0) ? C6 : 0.0f;
    float s1 = (inr && q >= -1 && q <= 9) ? C6 : 0.0f;
    float s2 = (inr && q >= -2 && q <= 8) ? C6 : 0.0f;
    float s3 = (inr && q <= 7) ? C6 : 0.0f;
    float b0 = um * um * um * s0;
    float b1 = fmaf(3.0f, u3, fmaf(-6.0f, uu, 4.0f)) * s1;
    float b2 = fmaf(-3.0f, u3, fmaf(3.0f, uu, fmaf(3.0f, u, 1.0f))) * s2;
    float b3 = u3 * s3;
    bf16x2 k01; k01[0] = (__bf16)b0; k01[1] = (__bf16)b1;
    bf16x2 k23; k23[0] = (__bf16)b2; k23[1] = (__bf16)b3;
    uint K01 = __builtin_bit_cast(uint, k01);
    uint K23 = __builtin_bit_cast(uint, k23);
    int r  = q & 1;
    int e0 = q & ~1;
    uint P0 = r ? (K01 << 16) : K01;
    uint P1 = r ? ((K01 >> 16) | (K23 << 16)) : K23;
    uint P2 = r ? (K23 >> 16) : 0u;
    #pragma unroll
    for (int pi = 0; pi < 6; ++pi) {
        int d = 2 * pi - e0;
        p[pi] = (d == 0) ? P0 : (d == 2) ? P1 : (d == 4) ? P2 : 0u;
    }
    p[5] = (p[5] & 0xFFFFu) | ((uint)f2bf(xx) << 16);   // slot 11 = raw x
}

// stage 4 features -> 96 B via 12x ds_write_b64 (low-conflict pattern)
__device__ __forceinline__ void stage4(float4 xv, ushort* dst) {
    uint p[4][6];
    eval12(xv.x, p[0]);
    eval12(xv.y, p[1]);
    eval12(xv.z, p[2]);
    eval12(xv.w, p[3]);
    #pragma unroll
    for (int c = 0; c < 4; ++c) {
        uint2 w0; w0.x = p[c][0]; w0.y = p[c][1];
        uint2 w1; w1.x = p[c][2]; w1.y = p[c][3];
        uint2 w2; w2.x = p[c][4]; w2.y = p[c][5];
        *(uint2*)&dst[c * 12 + 0] = w0;
        *(uint2*)&dst[c * 12 + 4] = w1;
        *(uint2*)&dst[c * 12 + 8] = w2;
    }
}

// ---- fused GEMM: block 128x128, single-buffer A, 3 blocks/CU ---------------
// grid 1024: bx = mb*16 + cg*4 + kp  ->  XCD = (cg*4+kp)%8: 2 cg/XCD (B 3.1MB, L2-fit)
__global__ __launch_bounds__(256, 3) void kan_gemm(const float* __restrict__ x,
                                                   float* __restrict__ out) {
    __shared__ __align__(16) ushort As[128 * AROW];   // 30720 B

    const int t    = threadIdx.x;
    const int lane = t & 63;
    const int wv   = t >> 6;          // 0..3
    const int wr   = wv >> 1;         // wave M half
    const int wc   = wv & 1;          // wave N half
    const int ln31 = lane & 31;
    const int half = lane >> 5;

    const int bx = blockIdx.x;
    const int mb = bx >> 4;           // 0..63
    const int cg = (bx >> 2) & 3;     // 128-col group
    const int kp = bx & 3;            // K quarter (128 feats, 16 groups)
    const int row_base = mb * 128;

    // staging: thread -> (row, 4 feats)
    const int srow = t >> 1;
    const int fq   = t & 1;
    const float* xp = x + (size_t)(row_base + srow) * IN_F + kp * 128 + fq * 4;
    ushort* const sb = &As[srow * AROW + fq * 48];

    const int ntg0 = cg * 4 + wc * 2;
    const uint4* Bp0 = (const uint4*)g_Wb + (size_t)ntg0 * K16S * 64 + lane;
    const uint4* Bp1 = Bp0 + (size_t)K16S * 64;

    f32x16 acc[2][2] = {};

    float4 xv = *(const float4*)xp;   // group 0 of this K-quarter

    #pragma unroll 1
    for (int gi = 0; gi < 16; ++gi) {
        const int g = kp * 16 + gi;   // global 8-feat group 0..63
        // B frags for this group
        uint4 breg[6][2];
        #pragma unroll
        for (int ks = 0; ks < 6; ++ks) {
            breg[ks][0] = Bp0[(size_t)(g * 6 + ks) * 64];
            breg[ks][1] = Bp1[(size_t)(g * 6 + ks) * 64];
        }
        // x prefetch for next group (clamped)
        const int gn = (gi + 1 < 16) ? gi + 1 : gi;
        float4 xn = *(const float4*)(xp + gn * 8);

        __syncthreads();              // prior iteration's A-frag reads done
        stage4(xv, sb);
        __syncthreads();              // publish A-tile

        #pragma unroll
        for (int ks = 0; ks < 6; ++ks) {
            uint4 a0 = *(const uint4*)&As[(wr * 64 + ln31) * AROW + ks * 16 + half * 8];
            uint4 a1 = *(const uint4*)&As[(wr * 64 + 32 + ln31) * AROW + ks * 16 + half * 8];
            bf16x8 af0 = __builtin_bit_cast(bf16x8, a0);
            bf16x8 af1 = __builtin_bit_cast(bf16x8, a1);
            bf16x8 bf0 = __builtin_bit_cast(bf16x8, breg[ks][0]);
            bf16x8 bf1 = __builtin_bit_cast(bf16x8, breg[ks][1]);
            acc[0][0] = __builtin_amdgcn_mfma_f32_32x32x16_bf16(af0, bf0, acc[0][0], 0, 0, 0);
            acc[0][1] = __builtin_amdgcn_mfma_f32_32x32x16_bf16(af0, bf1, acc[0][1], 0, 0, 0);
            acc[1][0] = __builtin_amdgcn_mfma_f32_32x32x16_bf16(af1, bf0, acc[1][0], 0, 0, 0);
            acc[1][1] = __builtin_amdgcn_mfma_f32_32x32x16_bf16(af1, bf1, acc[1][1], 0, 0, 0);
        }
        xv = xn;
    }

    // epilogue: C layout col=lane&31, row=(reg&3)+8*(reg>>2)+4*(lane>>5)
    #pragma unroll
    for (int mt = 0; mt < 2; ++mt) {
        #pragma unroll
        for (int nt2 = 0; nt2 < 2; ++nt2) {
            int rb = row_base + wr * 64 + mt * 32 + 4 * half;
            int cc = cg * 128 + wc * 64 + nt2 * 32 + ln31;
            #pragma unroll
            for (int reg = 0; reg < 16; ++reg) {
                int rr = rb + (reg & 3) + 8 * (reg >> 2);
                unsafeAtomicAdd(&out[(size_t)rr * OUT_F + cc], acc[mt][nt2][reg]);
            }
        }
    }
}

extern "C" void kernel_launch(void* const* d_in, const int* in_sizes, int n_in,
                              void* d_out, int out_size, void* d_ws, size_t ws_size,
                              hipStream_t stream) {
    const float* x  = (const float*)d_in[0];
    const float* bw = (const float*)d_in[1];
    const float* sw = (const float*)d_in[2];
    float* out = (float*)d_out;
    hipLaunchKernelGGL(prep_weights, dim3(1024), dim3(256), 0, stream, bw, sw, out);
    hipLaunchKernelGGL(kan_gemm, dim3(1024), dim3(256), 0, stream, x, out);
}